// Round 6
// baseline (265.642 us; speedup 1.0000x reference)
//
#include <hip/hip_runtime.h>
#include <math.h>

#define H 128
#define TOPK 5
#define INV_TEMP 5.0f
#define ZLD 2048      // z2t column stride (>= NRES, pow2)
#define ZN 8          // zero-nodes per group
#define JQ 512        // j-columns per task (quarter of ZLD)

typedef __attribute__((ext_vector_type(8))) short short8;
typedef __attribute__((ext_vector_type(4))) float f32x4;

__device__ __forceinline__ unsigned bf16_rne(float x) {
  unsigned u = __float_as_uint(x);
  return (u + 0x7FFFu + ((u >> 16) & 1u)) >> 16;
}
__device__ __forceinline__ unsigned pk_bf16(float lo, float hi) {
  return bf16_rne(lo) | (bf16_rne(hi) << 16);
}

// ---------------- degree count ----------------
__global__ __launch_bounds__(256) void deg_kernel(
    const int* __restrict__ src, const int* __restrict__ dst,
    int* __restrict__ in_deg, int* __restrict__ out_deg, int E)
{
  int e = blockIdx.x * 256 + threadIdx.x;
  if (e < E) {
    atomicAdd(&in_deg[dst[e]], 1);
    atomicAdd(&out_deg[src[e]], 1);
  }
}

// ---------------- exclusive scan of in_deg -> offs[0..N] ----------------
__global__ __launch_bounds__(1024) void scan_kernel(
    const int* __restrict__ deg, int* __restrict__ offs, int n)
{
  __shared__ int sums[1024];
  int tid = threadIdx.x;
  int per = (((n + 1023) >> 10) + 3) & ~3;   // multiple of 4 for int4
  int start = tid * per;
  int end = min(start + per, n);
  int s = 0;
  int i = start;
  for (; i + 4 <= end; i += 4) {
    int4 v = *(const int4*)&deg[i];
    s += v.x + v.y + v.z + v.w;
  }
  for (; i < end; ++i) s += deg[i];
  sums[tid] = s;
  __syncthreads();
  for (int off = 1; off < 1024; off <<= 1) {
    int v = (tid >= off) ? sums[tid - off] : 0;
    __syncthreads();
    sums[tid] += v;
    __syncthreads();
  }
  int run = (tid == 0) ? 0 : sums[tid - 1];
  i = start;
  for (; i + 4 <= end; i += 4) {
    int4 v = *(const int4*)&deg[i];
    int4 o;
    o.x = run; run += v.x;
    o.y = run; run += v.y;
    o.z = run; run += v.z;
    o.w = run; run += v.w;
    *(int4*)&offs[i] = o;
  }
  for (; i < end; ++i) { offs[i] = run; run += deg[i]; }
  if (tid == 1023) offs[n] = sums[1023];
}

// ---------------- bucket fill (payload = rel | inv<<16) ----------------
__global__ __launch_bounds__(256) void fill_kernel(
    const int* __restrict__ dst, const int* __restrict__ rel, const int* __restrict__ inv,
    const int* __restrict__ offs, int* __restrict__ cursor, int* __restrict__ bucket, int E)
{
  int e = blockIdx.x * 256 + threadIdx.x;
  if (e < E) {
    int d = dst[e];
    int pos = offs[d] + atomicAdd(&cursor[d], 1);
    bucket[pos] = rel[e] | (inv[e] << 16);
  }
}

// ---------------- prep: zerolist + W1/W2 -> bf16 + z2t normalize-transpose ----------------
__global__ __launch_bounds__(256) void prep_kernel(
    const int* __restrict__ in_deg, const int* __restrict__ out_deg,
    int* __restrict__ zlist, int* __restrict__ zcount, int N,
    const float* __restrict__ W1, const float* __restrict__ W2,
    unsigned short* __restrict__ W1b, unsigned short* __restrict__ W2b,
    const float* __restrict__ res, float* __restrict__ z2t, int NRES_)
{
  int nbz = (N + 255) >> 8;
  int b = blockIdx.x;
  if (b < nbz) {
    int n = b * 256 + threadIdx.x;
    if (n < N && (in_deg[n] + out_deg[n]) == 0) {
      int p = atomicAdd(zcount, 1);
      zlist[p] = n;
    }
  } else if (b < nbz + 32) {
    int b2 = b - nbz;              // 0..31
    const float* Wsrc = (b2 < 16) ? W1 : W2;
    unsigned short* Wdst = (b2 < 16) ? W1b : W2b;
    int base = (b2 & 15) * 1024 + threadIdx.x * 4;
    float4 v = *(const float4*)&Wsrc[base];
    uint2 p = make_uint2(pk_bf16(v.x, v.y), pk_bf16(v.z, v.w));
    *(uint2*)&Wdst[base] = p;
  } else {
    // l2-normalize res rows -> transposed z2t[k][j]; 4 rows/block (wave each)
    int r = (b - nbz - 32) * 4 + (threadIdx.x >> 6);
    int lane = threadIdx.x & 63;
    if (r < NRES_) {
      float x0 = res[(size_t)r * H + lane];
      float x1 = res[(size_t)r * H + lane + 64];
      float ss = x0 * x0 + x1 * x1;
      #pragma unroll
      for (int off = 32; off > 0; off >>= 1) ss += __shfl_xor(ss, off, 64);
      float iv = 1.0f / fmaxf(sqrtf(ss), 1e-12f);
      z2t[(size_t)lane * ZLD + r] = x0 * iv;
      z2t[(size_t)(lane + 64) * ZLD + r] = x1 * iv;
    }
  }
}

// ---------------- per-node mean gather (one wave per node) ----------------
__global__ __launch_bounds__(256) void gather_kernel(
    const int* __restrict__ offs, const int* __restrict__ bucket,
    const float* __restrict__ rhead, const float* __restrict__ rtail,
    float* __restrict__ feat, int N)
{
  int gid = blockIdx.x * 256 + threadIdx.x;
  int wid = gid >> 6;
  int lane = gid & 63;
  if (wid >= N) return;
  int b = offs[wid], e2 = offs[wid + 1];
  float a0 = 0.f, a1 = 0.f;
  int pay = (b < e2) ? bucket[b] : 0;
  for (int p = b; p < e2; ++p) {
    int pn = (p + 1 < e2) ? bucket[p + 1] : 0;   // prefetch next payload
    int r = pay & 0xFFFF;
    const float* row = ((pay >> 16) ? rhead : rtail) + (size_t)r * H;
    a0 += row[lane];
    a1 += row[lane + 64];
    pay = pn;
  }
  int deg = e2 - b;
  float sc = 1.0f / (float)(deg > 0 ? deg : 1);
  feat[(size_t)wid * H + lane] = a0 * sc;
  feat[(size_t)wid * H + lane + 64] = a1 * sc;
}

// ---------------- zero-node sims + partial top-5 per (group, j-quarter) ----------------
// Task = (group of ZN=8 zero-nodes) x (512-wide j quarter). Double-buffered
// 8-deep float2 prefetch (A/B, static-indexed) keeps L2 latency hidden;
// launch_bounds(256,2) gives the register budget for it.
__global__ __launch_bounds__(256, 2) void zero_sims_kernel(
    const int* __restrict__ zlist, const int* __restrict__ zcount,
    const float* __restrict__ ent, const float* __restrict__ z2t,
    float2* __restrict__ partials, int NRES_)
{
  __shared__ __align__(16) float z1s[ZN * H];    // 4 KB
  __shared__ __align__(8) float sims[ZN * JQ];   // 16 KB
  int t = threadIdx.x;
  int w = t >> 6;
  int lane = t & 63;
  int Z = *zcount;
  int ntasks = ((Z + ZN - 1) / ZN) << 2;
  for (int task = blockIdx.x; task < ntasks; task += gridDim.x) {
    int g = task >> 2, q = task & 3;
    int zi0 = g * ZN;
    int nv = min(ZN, Z - zi0);
    // ---- normalize z1 rows: wave w -> local nodes 2w, 2w+1 ----
    #pragma unroll
    for (int c = 0; c < 2; ++c) {
      int nl = w * 2 + c;
      float x0 = 0.f, x1 = 0.f;
      if (nl < nv) {
        int n = zlist[zi0 + nl];
        x0 = ent[(size_t)n * H + lane];
        x1 = ent[(size_t)n * H + lane + 64];
        float ss = x0 * x0 + x1 * x1;
        #pragma unroll
        for (int off = 32; off > 0; off >>= 1) ss += __shfl_xor(ss, off, 64);
        float iv = 1.0f / fmaxf(sqrtf(ss), 1e-12f);
        x0 *= iv; x1 *= iv;
      }
      z1s[nl * H + lane] = x0;
      z1s[nl * H + lane + 64] = x1;
    }
    __syncthreads();
    // ---- sims: thread t owns j-columns (2t, 2t+1); A/B prefetch pipeline ----
    {
      int jl0 = 2 * t;
      const float* zc = z2t + (size_t)q * JQ + jl0;
      float2 A[8], B[8];
      #pragma unroll
      for (int kk = 0; kk < 8; ++kk)
        A[kk] = *(const float2*)(zc + (size_t)kk * ZLD);
      float acc0[ZN], acc1[ZN];
      #pragma unroll
      for (int n = 0; n < ZN; ++n) { acc0[n] = 0.f; acc1[n] = 0.f; }
      #pragma unroll 2
      for (int k0 = 0; k0 < H; k0 += 16) {
        // prefetch B for k = k0+8 .. k0+15 (always in range)
        #pragma unroll
        for (int kk = 0; kk < 8; ++kk)
          B[kk] = *(const float2*)(zc + (size_t)(k0 + 8 + kk) * ZLD);
        // compute with A (k = k0 .. k0+7)
        #pragma unroll
        for (int n = 0; n < ZN; ++n) {
          float4 z0 = *(const float4*)&z1s[n * H + k0];
          float4 z1 = *(const float4*)&z1s[n * H + k0 + 4];
          acc0[n] = fmaf(z0.x, A[0].x, acc0[n]); acc1[n] = fmaf(z0.x, A[0].y, acc1[n]);
          acc0[n] = fmaf(z0.y, A[1].x, acc0[n]); acc1[n] = fmaf(z0.y, A[1].y, acc1[n]);
          acc0[n] = fmaf(z0.z, A[2].x, acc0[n]); acc1[n] = fmaf(z0.z, A[2].y, acc1[n]);
          acc0[n] = fmaf(z0.w, A[3].x, acc0[n]); acc1[n] = fmaf(z0.w, A[3].y, acc1[n]);
          acc0[n] = fmaf(z1.x, A[4].x, acc0[n]); acc1[n] = fmaf(z1.x, A[4].y, acc1[n]);
          acc0[n] = fmaf(z1.y, A[5].x, acc0[n]); acc1[n] = fmaf(z1.y, A[5].y, acc1[n]);
          acc0[n] = fmaf(z1.z, A[6].x, acc0[n]); acc1[n] = fmaf(z1.z, A[6].y, acc1[n]);
          acc0[n] = fmaf(z1.w, A[7].x, acc0[n]); acc1[n] = fmaf(z1.w, A[7].y, acc1[n]);
        }
        // prefetch A for k = k0+16 .. (wraps harmlessly to 0..7 on last iter)
        #pragma unroll
        for (int kk = 0; kk < 8; ++kk)
          A[kk] = *(const float2*)(zc + (size_t)((k0 + 16 + kk) & (H - 1)) * ZLD);
        // compute with B (k = k0+8 .. k0+15)
        #pragma unroll
        for (int n = 0; n < ZN; ++n) {
          float4 z0 = *(const float4*)&z1s[n * H + k0 + 8];
          float4 z1 = *(const float4*)&z1s[n * H + k0 + 12];
          acc0[n] = fmaf(z0.x, B[0].x, acc0[n]); acc1[n] = fmaf(z0.x, B[0].y, acc1[n]);
          acc0[n] = fmaf(z0.y, B[1].x, acc0[n]); acc1[n] = fmaf(z0.y, B[1].y, acc1[n]);
          acc0[n] = fmaf(z0.z, B[2].x, acc0[n]); acc1[n] = fmaf(z0.z, B[2].y, acc1[n]);
          acc0[n] = fmaf(z0.w, B[3].x, acc0[n]); acc1[n] = fmaf(z0.w, B[3].y, acc1[n]);
          acc0[n] = fmaf(z1.x, B[4].x, acc0[n]); acc1[n] = fmaf(z1.x, B[4].y, acc1[n]);
          acc0[n] = fmaf(z1.y, B[5].x, acc0[n]); acc1[n] = fmaf(z1.y, B[5].y, acc1[n]);
          acc0[n] = fmaf(z1.z, B[6].x, acc0[n]); acc1[n] = fmaf(z1.z, B[6].y, acc1[n]);
          acc0[n] = fmaf(z1.w, B[7].x, acc0[n]); acc1[n] = fmaf(z1.w, B[7].y, acc1[n]);
        }
      }
      int j0 = q * JQ + jl0;
      #pragma unroll
      for (int n = 0; n < ZN; ++n) {
        float v0 = (j0 < NRES_) ? acc0[n] : -1e30f;
        float v1 = (j0 + 1 < NRES_) ? acc1[n] : -1e30f;
        *(float2*)&sims[n * JQ + jl0] = make_float2(v0, v1);
      }
    }
    __syncthreads();
    // ---- per-wave top-5: wave w -> nodes 2w, 2w+1 ----
    #pragma unroll
    for (int c = 0; c < 2; ++c) {
      int nl = w * 2 + c;
      if (nl < nv) {
        float tv[TOPK]; int ti[TOPK];
        #pragma unroll
        for (int k = 0; k < TOPK; ++k) { tv[k] = -1e30f; ti[k] = 0x7fffffff; }
        #pragma unroll
        for (int i = 0; i < JQ / 64; ++i) {
          int jl = i * 64 + lane;
          float s = sims[nl * JQ + jl];
          int j = q * JQ + jl;
          if (s > tv[TOPK - 1] || (s == tv[TOPK - 1] && j < ti[TOPK - 1])) {
            tv[TOPK - 1] = s; ti[TOPK - 1] = j;
            #pragma unroll
            for (int k = TOPK - 1; k > 0; --k) {
              if (tv[k] > tv[k - 1] || (tv[k] == tv[k - 1] && ti[k] < ti[k - 1])) {
                float a = tv[k]; tv[k] = tv[k - 1]; tv[k - 1] = a;
                int bI = ti[k]; ti[k] = ti[k - 1]; ti[k - 1] = bI;
              }
            }
          }
        }
        #pragma unroll
        for (int r = 0; r < TOPK; ++r) {
          float bv = tv[0]; int bi = ti[0];
          #pragma unroll
          for (int k = 1; k < TOPK; ++k)
            if (tv[k] > bv || (tv[k] == bv && ti[k] < bi)) { bv = tv[k]; bi = ti[k]; }
          #pragma unroll
          for (int off = 32; off > 0; off >>= 1) {
            float ov = __shfl_xor(bv, off, 64);
            int oi = __shfl_xor(bi, off, 64);
            if (ov > bv || (ov == bv && oi < bi)) { bv = ov; bi = oi; }
          }
          if (lane == r)
            partials[((size_t)task * ZN + nl) * TOPK + r] =
                make_float2(bv, __int_as_float(bi));
          #pragma unroll
          for (int k = 0; k < TOPK; ++k)
            if (ti[k] == bi) tv[k] = -1e30f;
        }
      }
    }
    __syncthreads();
  }
}

// ---------------- merge 4 quarter top-5s -> softmax -> weighted sum ----------------
__global__ __launch_bounds__(256) void zmerge_kernel(
    const int* __restrict__ zlist, const int* __restrict__ zcount,
    const float2* __restrict__ partials, const float* __restrict__ res_raw,
    float* __restrict__ feat, int NRES_)
{
  int gid = blockIdx.x * 256 + threadIdx.x;
  int wid = gid >> 6;
  int lane = gid & 63;
  int nw = (gridDim.x * 256) >> 6;
  int Z = *zcount;
  for (int nz = wid; nz < Z; nz += nw) {
    int g = nz >> 3, w = nz & 7;
    float v = -1e30f; int idx = 0x7fffffff;
    if (lane < 4 * TOPK) {
      int q = lane / TOPK, k = lane - q * TOPK;
      float2 p = partials[((size_t)(g * 4 + q) * ZN + w) * TOPK + k];
      v = p.x; idx = __float_as_int(p.y);
    }
    bool used = false;
    float m = 0.f, wsum = 0.f, a0 = 0.f, a1 = 0.f;
    #pragma unroll
    for (int r = 0; r < TOPK; ++r) {
      float bv = used ? -1e31f : v;
      int bi = used ? 0x7fffffff : idx;
      #pragma unroll
      for (int off = 32; off > 0; off >>= 1) {
        float ov = __shfl_xor(bv, off, 64);
        int oi = __shfl_xor(bi, off, 64);
        if (ov > bv || (ov == bv && oi < bi)) { bv = ov; bi = oi; }
      }
      if (r == 0) m = bv;
      bool ok = (unsigned)bi < (unsigned)NRES_;
      float wk = ok ? expf((bv - m) * INV_TEMP) : 0.f;
      wsum += wk;
      const float* rr = res_raw + (size_t)(ok ? bi : 0) * H;
      a0 += wk * rr[lane];
      a1 += wk * rr[lane + 64];
      if (idx == bi) used = true;
    }
    float inv_ws = 1.0f / wsum;
    int n = zlist[nz];
    feat[(size_t)n * H + lane] = a0 * inv_ws;
    feat[(size_t)n * H + lane + 64] = a1 * inv_ws;
  }
}

// ---------------- fused 2-layer MLP via bf16 MFMA ----------------
__global__ __launch_bounds__(256) void mlp_kernel(
    const float* __restrict__ feat,
    const unsigned short* __restrict__ W1b, const float* __restrict__ b1,
    const unsigned short* __restrict__ W2b, const float* __restrict__ b2,
    float* __restrict__ out, int N)
{
  __shared__ float lds[64 * 128];   // 32 KB
  char* ldsb = (char*)lds;
  int t = threadIdx.x;
  int lane = t & 63;
  int w = t >> 6;
  int row0 = blockIdx.x * 64;

  for (int idx = t; idx < 64 * 32; idx += 256) {
    int r = idx >> 5, q = idx & 31;
    float4 v = make_float4(0.f, 0.f, 0.f, 0.f);
    if (row0 + r < N) v = *(const float4*)&feat[(size_t)(row0 + r) * H + q * 4];
    int byte = (r * 512 + q * 16) ^ ((r & 7) << 4);
    *(float4*)(ldsb + byte) = v;
  }
  __syncthreads();

  int m0 = w * 16;
  int col = lane & 15;
  int kg = lane >> 4;
  int am = m0 + col;
  int aswz = (am & 7) << 4;

  float bias1[8], bias2[8];
  #pragma unroll
  for (int nt = 0; nt < 8; ++nt) {
    bias1[nt] = b1[nt * 16 + col];
    bias2[nt] = b2[nt * 16 + col];
  }

  short8 afr[4];
  f32x4 acc[8];

  // ---- layer 1 ----
  #pragma unroll
  for (int ks = 0; ks < 4; ++ks) {
    int base = am * 512 + ks * 128 + kg * 32;
    float4 lo = *(float4*)(ldsb + (base ^ aswz));
    float4 hi = *(float4*)(ldsb + ((base + 16) ^ aswz));
    union { unsigned u[4]; short8 s; } cv;
    cv.u[0] = pk_bf16(lo.x, lo.y); cv.u[1] = pk_bf16(lo.z, lo.w);
    cv.u[2] = pk_bf16(hi.x, hi.y); cv.u[3] = pk_bf16(hi.z, hi.w);
    afr[ks] = cv.s;
  }
  #pragma unroll
  for (int nt = 0; nt < 8; ++nt) {
    f32x4 a; a[0] = a[1] = a[2] = a[3] = bias1[nt];
    acc[nt] = a;
    const unsigned short* wrow = W1b + (size_t)(nt * 16 + col) * H + kg * 8;
    #pragma unroll
    for (int ks = 0; ks < 4; ++ks) {
      union { int4 i; short8 s; } bv;
      bv.i = *(const int4*)(wrow + ks * 32);
      acc[nt] = __builtin_amdgcn_mfma_f32_16x16x32_bf16(afr[ks], bv.s, acc[nt], 0, 0, 0);
    }
  }
  __syncthreads();
  #pragma unroll
  for (int nt = 0; nt < 8; ++nt) {
    int n = nt * 16 + col;
    #pragma unroll
    for (int r = 0; r < 4; ++r) {
      int m = m0 + kg * 4 + r;
      int byte = (m * 512 + n * 4) ^ ((m & 7) << 4);
      *(float*)(ldsb + byte) = fmaxf(acc[nt][r], 0.f);
    }
  }
  __syncthreads();

  // ---- layer 2 ----
  #pragma unroll
  for (int ks = 0; ks < 4; ++ks) {
    int base = am * 512 + ks * 128 + kg * 32;
    float4 lo = *(float4*)(ldsb + (base ^ aswz));
    float4 hi = *(float4*)(ldsb + ((base + 16) ^ aswz));
    union { unsigned u[4]; short8 s; } cv;
    cv.u[0] = pk_bf16(lo.x, lo.y); cv.u[1] = pk_bf16(lo.z, lo.w);
    cv.u[2] = pk_bf16(hi.x, hi.y); cv.u[3] = pk_bf16(hi.z, hi.w);
    afr[ks] = cv.s;
  }
  #pragma unroll
  for (int nt = 0; nt < 8; ++nt) {
    f32x4 a; a[0] = a[1] = a[2] = a[3] = bias2[nt];
    acc[nt] = a;
    const unsigned short* wrow = W2b + (size_t)(nt * 16 + col) * H + kg * 8;
    #pragma unroll
    for (int ks = 0; ks < 4; ++ks) {
      union { int4 i; short8 s; } bv;
      bv.i = *(const int4*)(wrow + ks * 32);
      acc[nt] = __builtin_amdgcn_mfma_f32_16x16x32_bf16(afr[ks], bv.s, acc[nt], 0, 0, 0);
    }
  }
  #pragma unroll
  for (int nt = 0; nt < 8; ++nt) {
    int n = nt * 16 + col;
    #pragma unroll
    for (int r = 0; r < 4; ++r) {
      int m = row0 + m0 + kg * 4 + r;
      if (m < N) out[(size_t)m * H + n] = acc[nt][r];
    }
  }
}

extern "C" void kernel_launch(void* const* d_in, const int* in_sizes, int n_in,
                              void* d_out, int out_size, void* d_ws, size_t ws_size,
                              hipStream_t stream) {
  const int* src = (const int*)d_in[0];
  const int* dst = (const int*)d_in[1];
  const int* rel = (const int*)d_in[2];
  const int* inv = (const int*)d_in[3];
  const float* ent   = (const float*)d_in[4];
  const float* rhead = (const float*)d_in[5];
  const float* rtail = (const float*)d_in[6];
  const float* resent = (const float*)d_in[7];
  const float* W1 = (const float*)d_in[8];
  const float* b1 = (const float*)d_in[9];
  const float* W2 = (const float*)d_in[10];
  const float* b2 = (const float*)d_in[11];
  int E = in_sizes[0];
  int N = in_sizes[4] / H;
  int NRES_ = in_sizes[7] / H;
  float* out = (float*)d_out;

  char* ws = (char*)d_ws;
  size_t padN = (((size_t)N * 4) + 255) & ~(size_t)255;
  int* in_deg  = (int*)ws;
  int* out_deg = (int*)(ws + padN);
  int* cursor  = (int*)(ws + 2 * padN);
  int* zcount  = (int*)(ws + 3 * padN);
  size_t base = 3 * padN + 256;
  int* offs = (int*)(ws + base);  base += (((size_t)(N + 1) * 4) + 255) & ~(size_t)255;
  int* zlist = (int*)(ws + base); base += padN;
  int* bucket = (int*)(ws + base); base += (((size_t)E * 4) + 255) & ~(size_t)255;
  float* z2t = (float*)(ws + base); base += (size_t)H * ZLD * 4;
  unsigned short* W1b = (unsigned short*)(ws + base); base += (size_t)H * H * 2;
  unsigned short* W2b = (unsigned short*)(ws + base); base += (size_t)H * H * 2;
  float2* partials = (float2*)(ws + base);
  float* feat = out;  // reuse d_out as feat storage (per-row ownership in MLP)

  hipMemsetAsync(in_deg, 0, 3 * padN + 256, stream);

  int nbz = (N + 255) / 256;
  int nrb = (NRES_ + 3) / 4;
  deg_kernel<<<(E + 255) / 256, 256, 0, stream>>>(src, dst, in_deg, out_deg, E);
  scan_kernel<<<1, 1024, 0, stream>>>(in_deg, offs, N);
  fill_kernel<<<(E + 255) / 256, 256, 0, stream>>>(dst, rel, inv, offs, cursor, bucket, E);
  prep_kernel<<<nbz + 32 + nrb, 256, 0, stream>>>(in_deg, out_deg, zlist, zcount, N,
                                                  W1, W2, W1b, W2b, resent, z2t, NRES_);
  gather_kernel<<<(N + 3) / 4, 256, 0, stream>>>(offs, bucket, rhead, rtail, feat, N);
  zero_sims_kernel<<<1024, 256, 0, stream>>>(zlist, zcount, ent, z2t, partials, NRES_);
  zmerge_kernel<<<128, 256, 0, stream>>>(zlist, zcount, partials, resent, out, NRES_);
  mlp_kernel<<<(N + 63) / 64, 256, 0, stream>>>(feat, W1b, b1, W2b, b2, out, N);
}

// Round 7
// 257.834 us; speedup vs baseline: 1.0303x; 1.0303x over previous
//
#include <hip/hip_runtime.h>
#include <math.h>

#define H 128
#define TOPK 5
#define INV_TEMP 5.0f
#define ZLD 2048      // z2t column stride (>= NRES, pow2)
#define ZN 8          // zero-nodes per group
#define ZBLK 128      // extra blocks appended to gather grid for z1 normalize

typedef __attribute__((ext_vector_type(8))) short short8;
typedef __attribute__((ext_vector_type(4))) float f32x4;

__device__ __forceinline__ unsigned bf16_rne(float x) {
  unsigned u = __float_as_uint(x);
  return (u + 0x7FFFu + ((u >> 16) & 1u)) >> 16;
}
__device__ __forceinline__ unsigned pk_bf16(float lo, float hi) {
  return bf16_rne(lo) | (bf16_rne(hi) << 16);
}

// ---------------- degree count ----------------
__global__ __launch_bounds__(256) void deg_kernel(
    const int* __restrict__ src, const int* __restrict__ dst,
    int* __restrict__ in_deg, int* __restrict__ out_deg, int E)
{
  int e = blockIdx.x * 256 + threadIdx.x;
  if (e < E) {
    atomicAdd(&in_deg[dst[e]], 1);
    atomicAdd(&out_deg[src[e]], 1);
  }
}

// ---------------- exclusive scan of in_deg -> offs[0..N] ----------------
__global__ __launch_bounds__(1024) void scan_kernel(
    const int* __restrict__ deg, int* __restrict__ offs, int n)
{
  __shared__ int sums[1024];
  int tid = threadIdx.x;
  int per = (((n + 1023) >> 10) + 3) & ~3;   // multiple of 4 for int4
  int start = tid * per;
  int end = min(start + per, n);
  int s = 0;
  int i = start;
  for (; i + 4 <= end; i += 4) {
    int4 v = *(const int4*)&deg[i];
    s += v.x + v.y + v.z + v.w;
  }
  for (; i < end; ++i) s += deg[i];
  sums[tid] = s;
  __syncthreads();
  for (int off = 1; off < 1024; off <<= 1) {
    int v = (tid >= off) ? sums[tid - off] : 0;
    __syncthreads();
    sums[tid] += v;
    __syncthreads();
  }
  int run = (tid == 0) ? 0 : sums[tid - 1];
  i = start;
  for (; i + 4 <= end; i += 4) {
    int4 v = *(const int4*)&deg[i];
    int4 o;
    o.x = run; run += v.x;
    o.y = run; run += v.y;
    o.z = run; run += v.z;
    o.w = run; run += v.w;
    *(int4*)&offs[i] = o;
  }
  for (; i < end; ++i) { offs[i] = run; run += deg[i]; }
  if (tid == 1023) offs[n] = sums[1023];
}

// ---------------- bucket fill (payload = rel | inv<<16) ----------------
__global__ __launch_bounds__(256) void fill_kernel(
    const int* __restrict__ dst, const int* __restrict__ rel, const int* __restrict__ inv,
    const int* __restrict__ offs, int* __restrict__ cursor, int* __restrict__ bucket, int E)
{
  int e = blockIdx.x * 256 + threadIdx.x;
  if (e < E) {
    int d = dst[e];
    int pos = offs[d] + atomicAdd(&cursor[d], 1);
    bucket[pos] = rel[e] | (inv[e] << 16);
  }
}

// ---------------- prep: zerolist + W1/W2 -> bf16 + z2t normalize-transpose ----------------
__global__ __launch_bounds__(256) void prep_kernel(
    const int* __restrict__ in_deg, const int* __restrict__ out_deg,
    int* __restrict__ zlist, int* __restrict__ zcount, int N,
    const float* __restrict__ W1, const float* __restrict__ W2,
    unsigned short* __restrict__ W1b, unsigned short* __restrict__ W2b,
    const float* __restrict__ res, float* __restrict__ z2t, int NRES_)
{
  int nbz = (N + 255) >> 8;
  int b = blockIdx.x;
  if (b < nbz) {
    int n = b * 256 + threadIdx.x;
    if (n < N && (in_deg[n] + out_deg[n]) == 0) {
      int p = atomicAdd(zcount, 1);
      zlist[p] = n;
    }
  } else if (b < nbz + 32) {
    int b2 = b - nbz;              // 0..31
    const float* Wsrc = (b2 < 16) ? W1 : W2;
    unsigned short* Wdst = (b2 < 16) ? W1b : W2b;
    int base = (b2 & 15) * 1024 + threadIdx.x * 4;
    float4 v = *(const float4*)&Wsrc[base];
    uint2 p = make_uint2(pk_bf16(v.x, v.y), pk_bf16(v.z, v.w));
    *(uint2*)&Wdst[base] = p;
  } else {
    // l2-normalize res rows -> transposed z2t[k][j]; 4 rows/block (wave each)
    int r = (b - nbz - 32) * 4 + (threadIdx.x >> 6);
    int lane = threadIdx.x & 63;
    if (r < NRES_) {
      float x0 = res[(size_t)r * H + lane];
      float x1 = res[(size_t)r * H + lane + 64];
      float ss = x0 * x0 + x1 * x1;
      #pragma unroll
      for (int off = 32; off > 0; off >>= 1) ss += __shfl_xor(ss, off, 64);
      float iv = 1.0f / fmaxf(sqrtf(ss), 1e-12f);
      z2t[(size_t)lane * ZLD + r] = x0 * iv;
      z2t[(size_t)(lane + 64) * ZLD + r] = x1 * iv;
    }
  }
}

// ---------------- per-node mean gather + (appended blocks) z1 normalize ----------------
// Blocks >= GB: write l2-normalized ent rows of zero-total-degree nodes INTO
// feat[n] (gather skips exactly those rows -> no race). zero_sims reads them
// as z1; zmerge overwrites with the final embedding afterwards.
__global__ __launch_bounds__(256) void gather_kernel(
    const int* __restrict__ offs, const int* __restrict__ bucket,
    const int* __restrict__ out_deg,
    const float* __restrict__ rhead, const float* __restrict__ rtail,
    float* __restrict__ feat, int N, int GB,
    const int* __restrict__ zlist, const int* __restrict__ zcount,
    const float* __restrict__ ent)
{
  int lane = threadIdx.x & 63;
  if ((int)blockIdx.x >= GB) {
    int Z = *zcount;
    int wid0 = ((blockIdx.x - GB) << 2) + (threadIdx.x >> 6);
    int nwv = (gridDim.x - GB) << 2;
    for (int i = wid0; i < Z; i += nwv) {
      int n = zlist[i];
      float x0 = ent[(size_t)n * H + lane];
      float x1 = ent[(size_t)n * H + lane + 64];
      float ss = x0 * x0 + x1 * x1;
      #pragma unroll
      for (int off = 32; off > 0; off >>= 1) ss += __shfl_xor(ss, off, 64);
      float iv = 1.0f / fmaxf(sqrtf(ss), 1e-12f);
      feat[(size_t)n * H + lane] = x0 * iv;
      feat[(size_t)n * H + lane + 64] = x1 * iv;
    }
    return;
  }
  int wid = (blockIdx.x * 256 + threadIdx.x) >> 6;
  if (wid >= N) return;
  int b = offs[wid], e2 = offs[wid + 1];
  int deg = e2 - b;
  if (deg == 0 && out_deg[wid] == 0) return;   // z1 row lives here
  float a0 = 0.f, a1 = 0.f;
  int pay = (b < e2) ? bucket[b] : 0;
  for (int p = b; p < e2; ++p) {
    int pn = (p + 1 < e2) ? bucket[p + 1] : 0;   // prefetch next payload
    int r = pay & 0xFFFF;
    const float* row = ((pay >> 16) ? rhead : rtail) + (size_t)r * H;
    a0 += row[lane];
    a1 += row[lane + 64];
    pay = pn;
  }
  float sc = 1.0f / (float)(deg > 0 ? deg : 1);
  feat[(size_t)wid * H + lane] = a0 * sc;
  feat[(size_t)wid * H + lane + 64] = a1 * sc;
}

// ---------------- zero-node sims + partial top-5 per (group, j-half) ----------------
// Task = (group of ZN=8 zero-nodes) x (1024-wide j half). z1 rows read from
// GLOBAL memory at wave-uniform addresses -> compiler promotes to s_load
// (SGPR broadcast), taking z1 traffic off the LDS/VMEM pipes entirely.
// Thread owns 4 adjacent columns (one coalesced float4 z2t load per k).
__global__ __launch_bounds__(256) void zero_sims_kernel(
    const int* __restrict__ zlist, const int* __restrict__ zcount,
    const float* __restrict__ z1g, const float* __restrict__ z2t,
    float2* __restrict__ partials, int NRES_)
{
  __shared__ __align__(16) float sims[ZN * 1024];   // 32 KB
  int t = threadIdx.x;
  int w = t >> 6;
  int lane = t & 63;
  int Z = *zcount;
  if (Z <= 0) return;
  int ntasks = ((Z + ZN - 1) / ZN) * 2;
  for (int task = blockIdx.x; task < ntasks; task += gridDim.x) {
    int g = task >> 1, h = task & 1;
    int zi0 = g * ZN;
    int nv = min(ZN, Z - zi0);
    // uniform z1 row base pointers (SGPRs); clamp ragged tail
    const float* zp[ZN];
    #pragma unroll
    for (int n = 0; n < ZN; ++n) {
      int zi = zi0 + n; if (zi > Z - 1) zi = Z - 1;
      zp[n] = z1g + (size_t)zlist[zi] * H;
    }
    int jl0 = 4 * t;
    const float* zc = z2t + (size_t)h * 1024 + jl0;
    float acc[ZN][4];
    #pragma unroll
    for (int n = 0; n < ZN; ++n) {
      acc[n][0] = 0.f; acc[n][1] = 0.f; acc[n][2] = 0.f; acc[n][3] = 0.f;
    }
    #pragma unroll 2
    for (int k0 = 0; k0 < H; k0 += 4) {
      float4 c0 = *(const float4*)(zc + (size_t)(k0 + 0) * ZLD);
      float4 c1 = *(const float4*)(zc + (size_t)(k0 + 1) * ZLD);
      float4 c2 = *(const float4*)(zc + (size_t)(k0 + 2) * ZLD);
      float4 c3 = *(const float4*)(zc + (size_t)(k0 + 3) * ZLD);
      #pragma unroll
      for (int n = 0; n < ZN; ++n) {
        float4 z = *(const float4*)(zp[n] + k0);   // uniform -> s_load
        acc[n][0] = fmaf(z.x, c0.x, acc[n][0]);
        acc[n][1] = fmaf(z.x, c0.y, acc[n][1]);
        acc[n][2] = fmaf(z.x, c0.z, acc[n][2]);
        acc[n][3] = fmaf(z.x, c0.w, acc[n][3]);
        acc[n][0] = fmaf(z.y, c1.x, acc[n][0]);
        acc[n][1] = fmaf(z.y, c1.y, acc[n][1]);
        acc[n][2] = fmaf(z.y, c1.z, acc[n][2]);
        acc[n][3] = fmaf(z.y, c1.w, acc[n][3]);
        acc[n][0] = fmaf(z.z, c2.x, acc[n][0]);
        acc[n][1] = fmaf(z.z, c2.y, acc[n][1]);
        acc[n][2] = fmaf(z.z, c2.z, acc[n][2]);
        acc[n][3] = fmaf(z.z, c2.w, acc[n][3]);
        acc[n][0] = fmaf(z.w, c3.x, acc[n][0]);
        acc[n][1] = fmaf(z.w, c3.y, acc[n][1]);
        acc[n][2] = fmaf(z.w, c3.z, acc[n][2]);
        acc[n][3] = fmaf(z.w, c3.w, acc[n][3]);
      }
    }
    int j0g = h * 1024 + jl0;
    #pragma unroll
    for (int n = 0; n < ZN; ++n) {
      float4 v;
      v.x = (j0g + 0 < NRES_) ? acc[n][0] : -1e30f;
      v.y = (j0g + 1 < NRES_) ? acc[n][1] : -1e30f;
      v.z = (j0g + 2 < NRES_) ? acc[n][2] : -1e30f;
      v.w = (j0g + 3 < NRES_) ? acc[n][3] : -1e30f;
      *(float4*)&sims[n * 1024 + jl0] = v;
    }
    __syncthreads();
    // ---- per-wave top-5: wave w -> nodes 2w, 2w+1 ----
    #pragma unroll
    for (int c = 0; c < 2; ++c) {
      int nl = w * 2 + c;
      if (nl < nv) {
        float tv[TOPK]; int ti[TOPK];
        #pragma unroll
        for (int k = 0; k < TOPK; ++k) { tv[k] = -1e30f; ti[k] = 0x7fffffff; }
        #pragma unroll
        for (int i = 0; i < 1024 / 64; ++i) {
          int jl = i * 64 + lane;
          float s = sims[nl * 1024 + jl];
          int j = h * 1024 + jl;
          if (s > tv[TOPK - 1] || (s == tv[TOPK - 1] && j < ti[TOPK - 1])) {
            tv[TOPK - 1] = s; ti[TOPK - 1] = j;
            #pragma unroll
            for (int k = TOPK - 1; k > 0; --k) {
              if (tv[k] > tv[k - 1] || (tv[k] == tv[k - 1] && ti[k] < ti[k - 1])) {
                float a = tv[k]; tv[k] = tv[k - 1]; tv[k - 1] = a;
                int bI = ti[k]; ti[k] = ti[k - 1]; ti[k - 1] = bI;
              }
            }
          }
        }
        #pragma unroll
        for (int r = 0; r < TOPK; ++r) {
          float bv = tv[0]; int bi = ti[0];
          #pragma unroll
          for (int k = 1; k < TOPK; ++k)
            if (tv[k] > bv || (tv[k] == bv && ti[k] < bi)) { bv = tv[k]; bi = ti[k]; }
          #pragma unroll
          for (int off = 32; off > 0; off >>= 1) {
            float ov = __shfl_xor(bv, off, 64);
            int oi = __shfl_xor(bi, off, 64);
            if (ov > bv || (ov == bv && oi < bi)) { bv = ov; bi = oi; }
          }
          if (lane == r)
            partials[((size_t)task * ZN + nl) * TOPK + r] =
                make_float2(bv, __int_as_float(bi));
          #pragma unroll
          for (int k = 0; k < TOPK; ++k)
            if (ti[k] == bi) tv[k] = -1e30f;
        }
      }
    }
    __syncthreads();   // before next task overwrites sims
  }
}

// ---------------- merge 2 half top-5s -> softmax -> weighted sum ----------------
__global__ __launch_bounds__(256) void zmerge_kernel(
    const int* __restrict__ zlist, const int* __restrict__ zcount,
    const float2* __restrict__ partials, const float* __restrict__ res_raw,
    float* __restrict__ feat, int NRES_)
{
  int gid = blockIdx.x * 256 + threadIdx.x;
  int wid = gid >> 6;
  int lane = gid & 63;
  int nw = (gridDim.x * 256) >> 6;
  int Z = *zcount;
  for (int nz = wid; nz < Z; nz += nw) {
    int g = nz >> 3, w = nz & 7;
    float v = -1e30f; int idx = 0x7fffffff;
    if (lane < 2 * TOPK) {
      int q = lane / TOPK, k = lane - q * TOPK;
      float2 p = partials[((size_t)(g * 2 + q) * ZN + w) * TOPK + k];
      v = p.x; idx = __float_as_int(p.y);
    }
    bool used = false;
    float m = 0.f, wsum = 0.f, a0 = 0.f, a1 = 0.f;
    #pragma unroll
    for (int r = 0; r < TOPK; ++r) {
      float bv = used ? -1e31f : v;
      int bi = used ? 0x7fffffff : idx;
      #pragma unroll
      for (int off = 32; off > 0; off >>= 1) {
        float ov = __shfl_xor(bv, off, 64);
        int oi = __shfl_xor(bi, off, 64);
        if (ov > bv || (ov == bv && oi < bi)) { bv = ov; bi = oi; }
      }
      if (r == 0) m = bv;
      bool ok = (unsigned)bi < (unsigned)NRES_;
      float wk = ok ? expf((bv - m) * INV_TEMP) : 0.f;
      wsum += wk;
      const float* rr = res_raw + (size_t)(ok ? bi : 0) * H;
      a0 += wk * rr[lane];
      a1 += wk * rr[lane + 64];
      if (idx == bi) used = true;
    }
    float inv_ws = 1.0f / wsum;
    int n = zlist[nz];
    feat[(size_t)n * H + lane] = a0 * inv_ws;
    feat[(size_t)n * H + lane + 64] = a1 * inv_ws;
  }
}

// ---------------- fused 2-layer MLP via bf16 MFMA ----------------
__global__ __launch_bounds__(256) void mlp_kernel(
    const float* __restrict__ feat,
    const unsigned short* __restrict__ W1b, const float* __restrict__ b1,
    const unsigned short* __restrict__ W2b, const float* __restrict__ b2,
    float* __restrict__ out, int N)
{
  __shared__ float lds[64 * 128];   // 32 KB
  char* ldsb = (char*)lds;
  int t = threadIdx.x;
  int lane = t & 63;
  int w = t >> 6;
  int row0 = blockIdx.x * 64;

  for (int idx = t; idx < 64 * 32; idx += 256) {
    int r = idx >> 5, q = idx & 31;
    float4 v = make_float4(0.f, 0.f, 0.f, 0.f);
    if (row0 + r < N) v = *(const float4*)&feat[(size_t)(row0 + r) * H + q * 4];
    int byte = (r * 512 + q * 16) ^ ((r & 7) << 4);
    *(float4*)(ldsb + byte) = v;
  }
  __syncthreads();

  int m0 = w * 16;
  int col = lane & 15;
  int kg = lane >> 4;
  int am = m0 + col;
  int aswz = (am & 7) << 4;

  float bias1[8], bias2[8];
  #pragma unroll
  for (int nt = 0; nt < 8; ++nt) {
    bias1[nt] = b1[nt * 16 + col];
    bias2[nt] = b2[nt * 16 + col];
  }

  short8 afr[4];
  f32x4 acc[8];

  // ---- layer 1 ----
  #pragma unroll
  for (int ks = 0; ks < 4; ++ks) {
    int base = am * 512 + ks * 128 + kg * 32;
    float4 lo = *(float4*)(ldsb + (base ^ aswz));
    float4 hi = *(float4*)(ldsb + ((base + 16) ^ aswz));
    union { unsigned u[4]; short8 s; } cv;
    cv.u[0] = pk_bf16(lo.x, lo.y); cv.u[1] = pk_bf16(lo.z, lo.w);
    cv.u[2] = pk_bf16(hi.x, hi.y); cv.u[3] = pk_bf16(hi.z, hi.w);
    afr[ks] = cv.s;
  }
  #pragma unroll
  for (int nt = 0; nt < 8; ++nt) {
    f32x4 a; a[0] = a[1] = a[2] = a[3] = bias1[nt];
    acc[nt] = a;
    const unsigned short* wrow = W1b + (size_t)(nt * 16 + col) * H + kg * 8;
    #pragma unroll
    for (int ks = 0; ks < 4; ++ks) {
      union { int4 i; short8 s; } bv;
      bv.i = *(const int4*)(wrow + ks * 32);
      acc[nt] = __builtin_amdgcn_mfma_f32_16x16x32_bf16(afr[ks], bv.s, acc[nt], 0, 0, 0);
    }
  }
  __syncthreads();
  #pragma unroll
  for (int nt = 0; nt < 8; ++nt) {
    int n = nt * 16 + col;
    #pragma unroll
    for (int r = 0; r < 4; ++r) {
      int m = m0 + kg * 4 + r;
      int byte = (m * 512 + n * 4) ^ ((m & 7) << 4);
      *(float*)(ldsb + byte) = fmaxf(acc[nt][r], 0.f);
    }
  }
  __syncthreads();

  // ---- layer 2 ----
  #pragma unroll
  for (int ks = 0; ks < 4; ++ks) {
    int base = am * 512 + ks * 128 + kg * 32;
    float4 lo = *(float4*)(ldsb + (base ^ aswz));
    float4 hi = *(float4*)(ldsb + ((base + 16) ^ aswz));
    union { unsigned u[4]; short8 s; } cv;
    cv.u[0] = pk_bf16(lo.x, lo.y); cv.u[1] = pk_bf16(lo.z, lo.w);
    cv.u[2] = pk_bf16(hi.x, hi.y); cv.u[3] = pk_bf16(hi.z, hi.w);
    afr[ks] = cv.s;
  }
  #pragma unroll
  for (int nt = 0; nt < 8; ++nt) {
    f32x4 a; a[0] = a[1] = a[2] = a[3] = bias2[nt];
    acc[nt] = a;
    const unsigned short* wrow = W2b + (size_t)(nt * 16 + col) * H + kg * 8;
    #pragma unroll
    for (int ks = 0; ks < 4; ++ks) {
      union { int4 i; short8 s; } bv;
      bv.i = *(const int4*)(wrow + ks * 32);
      acc[nt] = __builtin_amdgcn_mfma_f32_16x16x32_bf16(afr[ks], bv.s, acc[nt], 0, 0, 0);
    }
  }
  #pragma unroll
  for (int nt = 0; nt < 8; ++nt) {
    int n = nt * 16 + col;
    #pragma unroll
    for (int r = 0; r < 4; ++r) {
      int m = row0 + m0 + kg * 4 + r;
      if (m < N) out[(size_t)m * H + n] = acc[nt][r];
    }
  }
}

extern "C" void kernel_launch(void* const* d_in, const int* in_sizes, int n_in,
                              void* d_out, int out_size, void* d_ws, size_t ws_size,
                              hipStream_t stream) {
  const int* src = (const int*)d_in[0];
  const int* dst = (const int*)d_in[1];
  const int* rel = (const int*)d_in[2];
  const int* inv = (const int*)d_in[3];
  const float* ent   = (const float*)d_in[4];
  const float* rhead = (const float*)d_in[5];
  const float* rtail = (const float*)d_in[6];
  const float* resent = (const float*)d_in[7];
  const float* W1 = (const float*)d_in[8];
  const float* b1 = (const float*)d_in[9];
  const float* W2 = (const float*)d_in[10];
  const float* b2 = (const float*)d_in[11];
  int E = in_sizes[0];
  int N = in_sizes[4] / H;
  int NRES_ = in_sizes[7] / H;
  float* out = (float*)d_out;

  char* ws = (char*)d_ws;
  size_t padN = (((size_t)N * 4) + 255) & ~(size_t)255;
  int* in_deg  = (int*)ws;
  int* out_deg = (int*)(ws + padN);
  int* cursor  = (int*)(ws + 2 * padN);
  int* zcount  = (int*)(ws + 3 * padN);
  size_t base = 3 * padN + 256;
  int* offs = (int*)(ws + base);  base += (((size_t)(N + 1) * 4) + 255) & ~(size_t)255;
  int* zlist = (int*)(ws + base); base += padN;
  int* bucket = (int*)(ws + base); base += (((size_t)E * 4) + 255) & ~(size_t)255;
  float* z2t = (float*)(ws + base); base += (size_t)H * ZLD * 4;
  unsigned short* W1b = (unsigned short*)(ws + base); base += (size_t)H * H * 2;
  unsigned short* W2b = (unsigned short*)(ws + base); base += (size_t)H * H * 2;
  float2* partials = (float2*)(ws + base);
  float* feat = out;  // reuse d_out as feat storage (per-row ownership in MLP)

  hipMemsetAsync(in_deg, 0, 3 * padN + 256, stream);

  int nbz = (N + 255) / 256;
  int nrb = (NRES_ + 3) / 4;
  int GB = (N + 3) / 4;
  deg_kernel<<<(E + 255) / 256, 256, 0, stream>>>(src, dst, in_deg, out_deg, E);
  scan_kernel<<<1, 1024, 0, stream>>>(in_deg, offs, N);
  fill_kernel<<<(E + 255) / 256, 256, 0, stream>>>(dst, rel, inv, offs, cursor, bucket, E);
  prep_kernel<<<nbz + 32 + nrb, 256, 0, stream>>>(in_deg, out_deg, zlist, zcount, N,
                                                  W1, W2, W1b, W2b, resent, z2t, NRES_);
  gather_kernel<<<GB + ZBLK, 256, 0, stream>>>(offs, bucket, out_deg, rhead, rtail,
                                               feat, N, GB, zlist, zcount, ent);
  zero_sims_kernel<<<512, 256, 0, stream>>>(zlist, zcount, feat, z2t, partials, NRES_);
  zmerge_kernel<<<128, 256, 0, stream>>>(zlist, zcount, partials, resent, out, NRES_);
  mlp_kernel<<<(N + 63) / 64, 256, 0, stream>>>(feat, W1b, b1, W2b, b2, out, N);
}

// Round 8
// 250.335 us; speedup vs baseline: 1.0611x; 1.0300x over previous
//
#include <hip/hip_runtime.h>
#include <math.h>

#define H 128
#define TOPK 5
#define INV_TEMP 5.0f
#define ZLD 2064      // z2t row stride in floats: 8256 B, NON-power-of-2 (kills L2 set aliasing), 16B-aligned
#define ZN 8          // zero-nodes per group
#define JQ 512        // j-columns per task (quarter of NRES)
#define ZBLK 128      // extra blocks appended to gather grid for z1 normalize

typedef __attribute__((ext_vector_type(8))) short short8;
typedef __attribute__((ext_vector_type(4))) float f32x4;

__device__ __forceinline__ unsigned bf16_rne(float x) {
  unsigned u = __float_as_uint(x);
  return (u + 0x7FFFu + ((u >> 16) & 1u)) >> 16;
}
__device__ __forceinline__ unsigned pk_bf16(float lo, float hi) {
  return bf16_rne(lo) | (bf16_rne(hi) << 16);
}

// ---------------- degree count ----------------
__global__ __launch_bounds__(256) void deg_kernel(
    const int* __restrict__ src, const int* __restrict__ dst,
    int* __restrict__ in_deg, int* __restrict__ out_deg, int E)
{
  int e = blockIdx.x * 256 + threadIdx.x;
  if (e < E) {
    atomicAdd(&in_deg[dst[e]], 1);
    atomicAdd(&out_deg[src[e]], 1);
  }
}

// ---------------- fused: scan (block 0) + zerolist + W->bf16 + z2t norm-transpose ----------------
__global__ __launch_bounds__(1024) void prep_kernel(
    const int* __restrict__ in_deg, const int* __restrict__ out_deg,
    int* __restrict__ offs,
    int* __restrict__ zlist, int* __restrict__ zcount, int N,
    const float* __restrict__ W1, const float* __restrict__ W2,
    unsigned short* __restrict__ W1b, unsigned short* __restrict__ W2b,
    const float* __restrict__ res, float* __restrict__ z2t, int NRES_)
{
  __shared__ int sums[1024];
  int b = blockIdx.x;
  int nbz = (N + 1023) >> 10;
  if (b == 0) {
    // exclusive scan of in_deg -> offs[0..N]
    int tid = threadIdx.x;
    int per = (((N + 1023) >> 10) + 3) & ~3;
    int start = tid * per;
    int end = min(start + per, N);
    int s = 0;
    int i = start;
    for (; i + 4 <= end; i += 4) {
      int4 v = *(const int4*)&in_deg[i];
      s += v.x + v.y + v.z + v.w;
    }
    for (; i < end; ++i) s += in_deg[i];
    sums[tid] = s;
    __syncthreads();
    for (int off = 1; off < 1024; off <<= 1) {
      int v = (tid >= off) ? sums[tid - off] : 0;
      __syncthreads();
      sums[tid] += v;
      __syncthreads();
    }
    int run = (tid == 0) ? 0 : sums[tid - 1];
    i = start;
    for (; i + 4 <= end; i += 4) {
      int4 v = *(const int4*)&in_deg[i];
      int4 o;
      o.x = run; run += v.x;
      o.y = run; run += v.y;
      o.z = run; run += v.z;
      o.w = run; run += v.w;
      *(int4*)&offs[i] = o;
    }
    for (; i < end; ++i) { offs[i] = run; run += in_deg[i]; }
    if (tid == 1023) offs[N] = sums[1023];
  } else if (b <= nbz) {
    int n = (b - 1) * 1024 + threadIdx.x;
    if (n < N && (in_deg[n] + out_deg[n]) == 0) {
      int p = atomicAdd(zcount, 1);
      zlist[p] = n;
    }
  } else if (b <= nbz + 8) {
    int b2 = b - nbz - 1;            // 0..7
    const float* Wsrc = (b2 < 4) ? W1 : W2;
    unsigned short* Wdst = (b2 < 4) ? W1b : W2b;
    int base = (b2 & 3) * 4096 + threadIdx.x * 4;
    float4 v = *(const float4*)&Wsrc[base];
    uint2 p = make_uint2(pk_bf16(v.x, v.y), pk_bf16(v.z, v.w));
    *(uint2*)&Wdst[base] = p;
  } else {
    // l2-normalize res rows -> transposed z2t[k][j]; 16 rows/block (wave each)
    int r = (b - nbz - 9) * 16 + (threadIdx.x >> 6);
    int lane = threadIdx.x & 63;
    if (r < NRES_) {
      float x0 = res[(size_t)r * H + lane];
      float x1 = res[(size_t)r * H + lane + 64];
      float ss = x0 * x0 + x1 * x1;
      #pragma unroll
      for (int off = 32; off > 0; off >>= 1) ss += __shfl_xor(ss, off, 64);
      float iv = 1.0f / fmaxf(sqrtf(ss), 1e-12f);
      z2t[(size_t)lane * ZLD + r] = x0 * iv;
      z2t[(size_t)(lane + 64) * ZLD + r] = x1 * iv;
    }
  }
}

// ---------------- bucket fill (payload = rel | inv<<16) ----------------
__global__ __launch_bounds__(256) void fill_kernel(
    const int* __restrict__ dst, const int* __restrict__ rel, const int* __restrict__ inv,
    const int* __restrict__ offs, int* __restrict__ cursor, int* __restrict__ bucket, int E)
{
  int e = blockIdx.x * 256 + threadIdx.x;
  if (e < E) {
    int d = dst[e];
    int pos = offs[d] + atomicAdd(&cursor[d], 1);
    bucket[pos] = rel[e] | (inv[e] << 16);
  }
}

// ---------------- per-node mean gather + (appended blocks) z1 normalize ----------------
__global__ __launch_bounds__(256) void gather_kernel(
    const int* __restrict__ offs, const int* __restrict__ bucket,
    const int* __restrict__ out_deg,
    const float* __restrict__ rhead, const float* __restrict__ rtail,
    float* __restrict__ feat, int N, int GB,
    const int* __restrict__ zlist, const int* __restrict__ zcount,
    const float* __restrict__ ent)
{
  int lane = threadIdx.x & 63;
  if ((int)blockIdx.x >= GB) {
    int Z = *zcount;
    int wid0 = ((blockIdx.x - GB) << 2) + (threadIdx.x >> 6);
    int nwv = (gridDim.x - GB) << 2;
    for (int i = wid0; i < Z; i += nwv) {
      int n = zlist[i];
      float x0 = ent[(size_t)n * H + lane];
      float x1 = ent[(size_t)n * H + lane + 64];
      float ss = x0 * x0 + x1 * x1;
      #pragma unroll
      for (int off = 32; off > 0; off >>= 1) ss += __shfl_xor(ss, off, 64);
      float iv = 1.0f / fmaxf(sqrtf(ss), 1e-12f);
      feat[(size_t)n * H + lane] = x0 * iv;
      feat[(size_t)n * H + lane + 64] = x1 * iv;
    }
    return;
  }
  int wid = (blockIdx.x * 256 + threadIdx.x) >> 6;
  if (wid >= N) return;
  int b = offs[wid], e2 = offs[wid + 1];
  int deg = e2 - b;
  if (deg == 0 && out_deg[wid] == 0) return;   // z1 row lives here
  float a0 = 0.f, a1 = 0.f;
  int pay = (b < e2) ? bucket[b] : 0;
  for (int p = b; p < e2; ++p) {
    int pn = (p + 1 < e2) ? bucket[p + 1] : 0;   // prefetch next payload
    int r = pay & 0xFFFF;
    const float* row = ((pay >> 16) ? rhead : rtail) + (size_t)r * H;
    a0 += row[lane];
    a1 += row[lane + 64];
    pay = pn;
  }
  float sc = 1.0f / (float)(deg > 0 ? deg : 1);
  feat[(size_t)wid * H + lane] = a0 * sc;
  feat[(size_t)wid * H + lane + 64] = a1 * sc;
}

// ---------------- zero-node sims + partial top-5 per (group, j-quarter) ----------------
// Task = (group of ZN=8 zero-nodes) x (512-wide j quarter); ntasks=1024 ->
// 4 blocks/CU. z1 rows via wave-uniform global reads (s_load / SGPR
// broadcast). z2t rows at NON-power-of-2 stride ZLD=2064.
__global__ __launch_bounds__(256) void zero_sims_kernel(
    const int* __restrict__ zlist, const int* __restrict__ zcount,
    const float* __restrict__ z1g, const float* __restrict__ z2t,
    float2* __restrict__ partials, int NRES_)
{
  __shared__ __align__(16) float sims[ZN * JQ];   // 16 KB
  int t = threadIdx.x;
  int w = t >> 6;
  int lane = t & 63;
  int Z = *zcount;
  if (Z <= 0) return;
  int ntasks = ((Z + ZN - 1) / ZN) * 4;
  for (int task = blockIdx.x; task < ntasks; task += gridDim.x) {
    int g = task >> 2, q = task & 3;
    int zi0 = g * ZN;
    int nv = min(ZN, Z - zi0);
    // uniform z1 row base pointers (SGPRs); clamp ragged tail
    const float* zp[ZN];
    #pragma unroll
    for (int n = 0; n < ZN; ++n) {
      int zi = zi0 + n; if (zi > Z - 1) zi = Z - 1;
      zp[n] = z1g + (size_t)zlist[zi] * H;
    }
    int jl0 = 2 * t;
    const float* zc = z2t + q * JQ + jl0;
    float acc[ZN][2];
    #pragma unroll
    for (int n = 0; n < ZN; ++n) { acc[n][0] = 0.f; acc[n][1] = 0.f; }
    #pragma unroll 2
    for (int k0 = 0; k0 < H; k0 += 4) {
      float2 c0 = *(const float2*)(zc + (size_t)(k0 + 0) * ZLD);
      float2 c1 = *(const float2*)(zc + (size_t)(k0 + 1) * ZLD);
      float2 c2 = *(const float2*)(zc + (size_t)(k0 + 2) * ZLD);
      float2 c3 = *(const float2*)(zc + (size_t)(k0 + 3) * ZLD);
      #pragma unroll
      for (int n = 0; n < ZN; ++n) {
        float4 z = *(const float4*)(zp[n] + k0);   // uniform -> s_load
        acc[n][0] = fmaf(z.x, c0.x, acc[n][0]);
        acc[n][1] = fmaf(z.x, c0.y, acc[n][1]);
        acc[n][0] = fmaf(z.y, c1.x, acc[n][0]);
        acc[n][1] = fmaf(z.y, c1.y, acc[n][1]);
        acc[n][0] = fmaf(z.z, c2.x, acc[n][0]);
        acc[n][1] = fmaf(z.z, c2.y, acc[n][1]);
        acc[n][0] = fmaf(z.w, c3.x, acc[n][0]);
        acc[n][1] = fmaf(z.w, c3.y, acc[n][1]);
      }
    }
    int j0g = q * JQ + jl0;
    #pragma unroll
    for (int n = 0; n < ZN; ++n) {
      float v0 = (j0g + 0 < NRES_) ? acc[n][0] : -1e30f;
      float v1 = (j0g + 1 < NRES_) ? acc[n][1] : -1e30f;
      *(float2*)&sims[n * JQ + jl0] = make_float2(v0, v1);
    }
    __syncthreads();
    // ---- per-wave top-5: wave w -> nodes 2w, 2w+1 ----
    #pragma unroll
    for (int c = 0; c < 2; ++c) {
      int nl = w * 2 + c;
      if (nl < nv) {
        float tv[TOPK]; int ti[TOPK];
        #pragma unroll
        for (int k = 0; k < TOPK; ++k) { tv[k] = -1e30f; ti[k] = 0x7fffffff; }
        #pragma unroll
        for (int i = 0; i < JQ / 64; ++i) {
          int jl = i * 64 + lane;
          float s = sims[nl * JQ + jl];
          int j = q * JQ + jl;
          if (s > tv[TOPK - 1] || (s == tv[TOPK - 1] && j < ti[TOPK - 1])) {
            tv[TOPK - 1] = s; ti[TOPK - 1] = j;
            #pragma unroll
            for (int k = TOPK - 1; k > 0; --k) {
              if (tv[k] > tv[k - 1] || (tv[k] == tv[k - 1] && ti[k] < ti[k - 1])) {
                float a = tv[k]; tv[k] = tv[k - 1]; tv[k - 1] = a;
                int bI = ti[k]; ti[k] = ti[k - 1]; ti[k - 1] = bI;
              }
            }
          }
        }
        #pragma unroll
        for (int r = 0; r < TOPK; ++r) {
          float bv = tv[0]; int bi = ti[0];
          #pragma unroll
          for (int k = 1; k < TOPK; ++k)
            if (tv[k] > bv || (tv[k] == bv && ti[k] < bi)) { bv = tv[k]; bi = ti[k]; }
          #pragma unroll
          for (int off = 32; off > 0; off >>= 1) {
            float ov = __shfl_xor(bv, off, 64);
            int oi = __shfl_xor(bi, off, 64);
            if (ov > bv || (ov == bv && oi < bi)) { bv = ov; bi = oi; }
          }
          if (lane == r)
            partials[((size_t)task * ZN + nl) * TOPK + r] =
                make_float2(bv, __int_as_float(bi));
          #pragma unroll
          for (int k = 0; k < TOPK; ++k)
            if (ti[k] == bi) tv[k] = -1e30f;
        }
      }
    }
    __syncthreads();   // before next task overwrites sims
  }
}

// ---------------- merge 4 quarter top-5s -> softmax -> weighted sum ----------------
__global__ __launch_bounds__(256) void zmerge_kernel(
    const int* __restrict__ zlist, const int* __restrict__ zcount,
    const float2* __restrict__ partials, const float* __restrict__ res_raw,
    float* __restrict__ feat, int NRES_)
{
  int gid = blockIdx.x * 256 + threadIdx.x;
  int wid = gid >> 6;
  int lane = gid & 63;
  int nw = (gridDim.x * 256) >> 6;
  int Z = *zcount;
  for (int nz = wid; nz < Z; nz += nw) {
    int g = nz >> 3, w = nz & 7;
    float v = -1e30f; int idx = 0x7fffffff;
    if (lane < 4 * TOPK) {
      int q = lane / TOPK, k = lane - q * TOPK;
      float2 p = partials[((size_t)(g * 4 + q) * ZN + w) * TOPK + k];
      v = p.x; idx = __float_as_int(p.y);
    }
    bool used = false;
    float m = 0.f, wsum = 0.f, a0 = 0.f, a1 = 0.f;
    #pragma unroll
    for (int r = 0; r < TOPK; ++r) {
      float bv = used ? -1e31f : v;
      int bi = used ? 0x7fffffff : idx;
      #pragma unroll
      for (int off = 32; off > 0; off >>= 1) {
        float ov = __shfl_xor(bv, off, 64);
        int oi = __shfl_xor(bi, off, 64);
        if (ov > bv || (ov == bv && oi < bi)) { bv = ov; bi = oi; }
      }
      if (r == 0) m = bv;
      bool ok = (unsigned)bi < (unsigned)NRES_;
      float wk = ok ? expf((bv - m) * INV_TEMP) : 0.f;
      wsum += wk;
      const float* rr = res_raw + (size_t)(ok ? bi : 0) * H;
      a0 += wk * rr[lane];
      a1 += wk * rr[lane + 64];
      if (idx == bi) used = true;
    }
    float inv_ws = 1.0f / wsum;
    int n = zlist[nz];
    feat[(size_t)n * H + lane] = a0 * inv_ws;
    feat[(size_t)n * H + lane + 64] = a1 * inv_ws;
  }
}

// ---------------- fused 2-layer MLP via bf16 MFMA ----------------
__global__ __launch_bounds__(256) void mlp_kernel(
    const float* __restrict__ feat,
    const unsigned short* __restrict__ W1b, const float* __restrict__ b1,
    const unsigned short* __restrict__ W2b, const float* __restrict__ b2,
    float* __restrict__ out, int N)
{
  __shared__ float lds[64 * 128];   // 32 KB
  char* ldsb = (char*)lds;
  int t = threadIdx.x;
  int lane = t & 63;
  int w = t >> 6;
  int row0 = blockIdx.x * 64;

  for (int idx = t; idx < 64 * 32; idx += 256) {
    int r = idx >> 5, q = idx & 31;
    float4 v = make_float4(0.f, 0.f, 0.f, 0.f);
    if (row0 + r < N) v = *(const float4*)&feat[(size_t)(row0 + r) * H + q * 4];
    int byte = (r * 512 + q * 16) ^ ((r & 7) << 4);
    *(float4*)(ldsb + byte) = v;
  }
  __syncthreads();

  int m0 = w * 16;
  int col = lane & 15;
  int kg = lane >> 4;
  int am = m0 + col;
  int aswz = (am & 7) << 4;

  float bias1[8], bias2[8];
  #pragma unroll
  for (int nt = 0; nt < 8; ++nt) {
    bias1[nt] = b1[nt * 16 + col];
    bias2[nt] = b2[nt * 16 + col];
  }

  short8 afr[4];
  f32x4 acc[8];

  // ---- layer 1 ----
  #pragma unroll
  for (int ks = 0; ks < 4; ++ks) {
    int base = am * 512 + ks * 128 + kg * 32;
    float4 lo = *(float4*)(ldsb + (base ^ aswz));
    float4 hi = *(float4*)(ldsb + ((base + 16) ^ aswz));
    union { unsigned u[4]; short8 s; } cv;
    cv.u[0] = pk_bf16(lo.x, lo.y); cv.u[1] = pk_bf16(lo.z, lo.w);
    cv.u[2] = pk_bf16(hi.x, hi.y); cv.u[3] = pk_bf16(hi.z, hi.w);
    afr[ks] = cv.s;
  }
  #pragma unroll
  for (int nt = 0; nt < 8; ++nt) {
    f32x4 a; a[0] = a[1] = a[2] = a[3] = bias1[nt];
    acc[nt] = a;
    const unsigned short* wrow = W1b + (size_t)(nt * 16 + col) * H + kg * 8;
    #pragma unroll
    for (int ks = 0; ks < 4; ++ks) {
      union { int4 i; short8 s; } bv;
      bv.i = *(const int4*)(wrow + ks * 32);
      acc[nt] = __builtin_amdgcn_mfma_f32_16x16x32_bf16(afr[ks], bv.s, acc[nt], 0, 0, 0);
    }
  }
  __syncthreads();
  #pragma unroll
  for (int nt = 0; nt < 8; ++nt) {
    int n = nt * 16 + col;
    #pragma unroll
    for (int r = 0; r < 4; ++r) {
      int m = m0 + kg * 4 + r;
      int byte = (m * 512 + n * 4) ^ ((m & 7) << 4);
      *(float*)(ldsb + byte) = fmaxf(acc[nt][r], 0.f);
    }
  }
  __syncthreads();

  // ---- layer 2 ----
  #pragma unroll
  for (int ks = 0; ks < 4; ++ks) {
    int base = am * 512 + ks * 128 + kg * 32;
    float4 lo = *(float4*)(ldsb + (base ^ aswz));
    float4 hi = *(float4*)(ldsb + ((base + 16) ^ aswz));
    union { unsigned u[4]; short8 s; } cv;
    cv.u[0] = pk_bf16(lo.x, lo.y); cv.u[1] = pk_bf16(lo.z, lo.w);
    cv.u[2] = pk_bf16(hi.x, hi.y); cv.u[3] = pk_bf16(hi.z, hi.w);
    afr[ks] = cv.s;
  }
  #pragma unroll
  for (int nt = 0; nt < 8; ++nt) {
    f32x4 a; a[0] = a[1] = a[2] = a[3] = bias2[nt];
    acc[nt] = a;
    const unsigned short* wrow = W2b + (size_t)(nt * 16 + col) * H + kg * 8;
    #pragma unroll
    for (int ks = 0; ks < 4; ++ks) {
      union { int4 i; short8 s; } bv;
      bv.i = *(const int4*)(wrow + ks * 32);
      acc[nt] = __builtin_amdgcn_mfma_f32_16x16x32_bf16(afr[ks], bv.s, acc[nt], 0, 0, 0);
    }
  }
  #pragma unroll
  for (int nt = 0; nt < 8; ++nt) {
    int n = nt * 16 + col;
    #pragma unroll
    for (int r = 0; r < 4; ++r) {
      int m = row0 + m0 + kg * 4 + r;
      if (m < N) out[(size_t)m * H + n] = acc[nt][r];
    }
  }
}

extern "C" void kernel_launch(void* const* d_in, const int* in_sizes, int n_in,
                              void* d_out, int out_size, void* d_ws, size_t ws_size,
                              hipStream_t stream) {
  const int* src = (const int*)d_in[0];
  const int* dst = (const int*)d_in[1];
  const int* rel = (const int*)d_in[2];
  const int* inv = (const int*)d_in[3];
  const float* ent   = (const float*)d_in[4];
  const float* rhead = (const float*)d_in[5];
  const float* rtail = (const float*)d_in[6];
  const float* resent = (const float*)d_in[7];
  const float* W1 = (const float*)d_in[8];
  const float* b1 = (const float*)d_in[9];
  const float* W2 = (const float*)d_in[10];
  const float* b2 = (const float*)d_in[11];
  int E = in_sizes[0];
  int N = in_sizes[4] / H;
  int NRES_ = in_sizes[7] / H;
  float* out = (float*)d_out;

  char* ws = (char*)d_ws;
  size_t padN = (((size_t)N * 4) + 255) & ~(size_t)255;
  int* in_deg  = (int*)ws;
  int* out_deg = (int*)(ws + padN);
  int* cursor  = (int*)(ws + 2 * padN);
  int* zcount  = (int*)(ws + 3 * padN);
  size_t base = 3 * padN + 256;
  int* offs = (int*)(ws + base);  base += (((size_t)(N + 1) * 4) + 255) & ~(size_t)255;
  int* zlist = (int*)(ws + base); base += padN;
  int* bucket = (int*)(ws + base); base += (((size_t)E * 4) + 255) & ~(size_t)255;
  float* z2t = (float*)(ws + base); base += (((size_t)H * ZLD * 4) + 255) & ~(size_t)255;
  unsigned short* W1b = (unsigned short*)(ws + base); base += (size_t)H * H * 2;
  unsigned short* W2b = (unsigned short*)(ws + base); base += (size_t)H * H * 2;
  float2* partials = (float2*)(ws + base);
  float* feat = out;  // reuse d_out as feat storage (per-row ownership in MLP)

  hipMemsetAsync(in_deg, 0, 3 * padN + 256, stream);

  int nbz = (N + 1023) / 1024;
  int nrb = (NRES_ + 15) / 16;
  int GB = (N + 3) / 4;
  deg_kernel<<<(E + 255) / 256, 256, 0, stream>>>(src, dst, in_deg, out_deg, E);
  prep_kernel<<<1 + nbz + 8 + nrb, 1024, 0, stream>>>(in_deg, out_deg, offs, zlist, zcount, N,
                                                      W1, W2, W1b, W2b, resent, z2t, NRES_);
  fill_kernel<<<(E + 255) / 256, 256, 0, stream>>>(dst, rel, inv, offs, cursor, bucket, E);
  gather_kernel<<<GB + ZBLK, 256, 0, stream>>>(offs, bucket, out_deg, rhead, rtail,
                                               feat, N, GB, zlist, zcount, ent);
  zero_sims_kernel<<<1024, 256, 0, stream>>>(zlist, zcount, feat, z2t, partials, NRES_);
  zmerge_kernel<<<128, 256, 0, stream>>>(zlist, zcount, partials, resent, out, NRES_);
  mlp_kernel<<<(N + 63) / 64, 256, 0, stream>>>(feat, W1b, b1, W2b, b2, out, N);
}